// Round 1
// baseline (289.623 us; speedup 1.0000x reference)
//
#include <hip/hip_runtime.h>

// DNNF fused pipeline for MI355X (gfx950).
// Stage 1: prep (x->bf16 + xsq, Wt = (W*M)^T bf16 K-major with mu appended, musq)
// Stage 2: bf16 MFMA GEMM 8192x11040x512, fused tanh + conj/formula segment
//          reduction (atomics into form_sum) for literal tiles; raw dot store
//          for mu tiles.
// Stage 3: RBF + softmax localization * dnnf.

#define BATCH 8192
#define IDIM 512
#define NFORM 256
#define NLIT 10752
#define WT_ROWS 11040  // NLIT + 288 (256 mu rows + 32 zero pad -> 3 tiles of 96)

#define BM 128
#define BN 96
#define BK 64
#define LITPAD 104  // floats per lit row in LDS (96 + 8 pad)

typedef __bf16 bf16x8 __attribute__((ext_vector_type(8)));
typedef float f32x4 __attribute__((ext_vector_type(4)));
typedef unsigned short u16;
typedef unsigned int u32;

__device__ __forceinline__ u16 f2bf(float f) {
  u32 u = __float_as_uint(f);
  u = (u + 0x7fffu + ((u >> 16) & 1u)) >> 16;  // RNE
  return (u16)u;
}

__device__ __forceinline__ float fast_tanh(float x) {
  // tanh(x) = 1 - 2/(exp(2x)+1); |err| < 1e-6, graceful at +-inf
  float e = __expf(2.0f * x);
  return 1.0f - 2.0f * __builtin_amdgcn_rcpf(e + 1.0f);
}

__device__ __forceinline__ void async_cp16(const void* g, void* l) {
  __builtin_amdgcn_global_load_lds(
      (const u32 __attribute__((address_space(1)))*)g,
      (u32 __attribute__((address_space(3)))*)l, 16, 0, 0);
}

// ---------------- prep kernels ----------------

__global__ __launch_bounds__(256) void prep_x(const float* __restrict__ x,
                                              u16* __restrict__ xb,
                                              float* __restrict__ xsq) {
  int row = blockIdx.x, t = threadIdx.x;
  const float2 v = ((const float2*)(x + (size_t)row * IDIM))[t];
  u32 packed = (u32)f2bf(v.x) | ((u32)f2bf(v.y) << 16);
  ((u32*)(xb + (size_t)row * IDIM))[t] = packed;
  __shared__ float red[256];
  red[t] = v.x * v.x + v.y * v.y;
  __syncthreads();
  for (int s = 128; s > 0; s >>= 1) {
    if (t < s) red[t] += red[t + s];
    __syncthreads();
  }
  if (t == 0) xsq[row] = red[0];
}

// Wt[l][k] = W[k][l] * M[k][l], bf16. 32x32 LDS transpose tiles.
__global__ __launch_bounds__(256) void prep_w(const float* __restrict__ W,
                                              const float* __restrict__ M,
                                              u16* __restrict__ wt) {
  __shared__ float tile[32][33];
  int l0 = blockIdx.x * 32, k0 = blockIdx.y * 32;
  int tx = threadIdx.x, ty = threadIdx.y;
#pragma unroll
  for (int i = 0; i < 4; ++i) {
    int kk = ty + i * 8;
    size_t g = (size_t)(k0 + kk) * NLIT + l0 + tx;
    tile[kk][tx] = W[g] * M[g];
  }
  __syncthreads();
#pragma unroll
  for (int i = 0; i < 4; ++i) {
    int ll = ty + i * 8;
    wt[(size_t)(l0 + ll) * IDIM + k0 + tx] = f2bf(tile[tx][ll]);
  }
}

// mu rows appended to Wt (rows NLIT..NLIT+255), musq, zero pad rows.
__global__ __launch_bounds__(256) void prep_mu(const float* __restrict__ mu,
                                               u16* __restrict__ wt,
                                               float* __restrict__ musq) {
  int b = blockIdx.x, t = threadIdx.x;
  if (b < 256) {
    float s = 0.f;
#pragma unroll
    for (int j = t; j < IDIM; j += 256) {
      float v = mu[(size_t)b * IDIM + j];
      wt[(size_t)(NLIT + b) * IDIM + j] = f2bf(v);
      s += v * v;
    }
    __shared__ float red[256];
    red[t] = s;
    __syncthreads();
    for (int sh = 128; sh > 0; sh >>= 1) {
      if (t < sh) red[t] += red[t + sh];
      __syncthreads();
    }
    if (t == 0) musq[b] = red[0];
  } else {
    int row = NLIT + 256 + (b - 256);  // 11008..11039
    for (int j = t; j < IDIM; j += 256) wt[(size_t)row * IDIM + j] = 0;
  }
}

// ---------------- main fused GEMM ----------------
// C/D frag map (verified m89/m91): col = lane&15, row = (lane>>4)*4 + reg.
// A/B frags: lane = idx + 16*kgroup holds 8 contiguous K elems (K-major LDS).
// XOR swizzle kg_phys = kg ^ (row&7) keeps global_load_lds chunks contiguous
// while making ds_read_b128 2-way max (free).

__global__ __launch_bounds__(256, 2) void dnnf_gemm(
    const u16* __restrict__ xb, const u16* __restrict__ wt,
    const float* __restrict__ bias, float* __restrict__ form_sum,
    float* __restrict__ dotbuf) {
  __shared__ __align__(16) char smraw[BM * LITPAD * 4];  // 53248 B (union)
  u16* sA = (u16*)smraw;          // BM x BK bf16 (16 KB)
  u16* sB = sA + BM * BK;         // BN x BK bf16 (12 KB)
  float* slit = (float*)smraw;    // BM x LITPAD floats (epilogue)

  const int tid = threadIdx.x;
  const int wave = tid >> 6, lane = tid & 63;
  const int m0 = blockIdx.y * BM;
  const int n0 = blockIdx.x * BN;
  const int q = lane >> 4, cn = lane & 15;

  f32x4 acc[2][6];
#pragma unroll
  for (int a = 0; a < 2; ++a)
#pragma unroll
    for (int b = 0; b < 6; ++b) acc[a][b] = (f32x4){0.f, 0.f, 0.f, 0.f};

  for (int kt = 0; kt < IDIM; kt += BK) {
    // stage A: 1024 16B chunks, 4 per thread, lane-contiguous LDS dests
#pragma unroll
    for (int i = 0; i < 4; ++i) {
      int c = tid + i * 256;
      int r = c >> 3, kgp = c & 7;
      int kg = kgp ^ (r & 7);
      async_cp16(xb + (size_t)(m0 + r) * IDIM + kt + kg * 8, (char*)sA + c * 16);
    }
    // stage B: 768 chunks, 3 per thread
#pragma unroll
    for (int i = 0; i < 3; ++i) {
      int c = tid + i * 256;
      int r = c >> 3, kgp = c & 7;
      int kg = kgp ^ (r & 7);
      async_cp16(wt + (size_t)(n0 + r) * IDIM + kt + kg * 8, (char*)sB + c * 16);
    }
    __syncthreads();  // compiler drains vmcnt before s_barrier

#pragma unroll
    for (int ks = 0; ks < 2; ++ks) {
      bf16x8 af[2], bfr[6];
#pragma unroll
      for (int mf = 0; mf < 2; ++mf) {
        int row = wave * 32 + mf * 16 + cn;
        int kg = (ks * 4 + q) ^ (row & 7);
        af[mf] = *(const bf16x8*)((const char*)sA + row * (BK * 2) + kg * 16);
      }
#pragma unroll
      for (int nf = 0; nf < 6; ++nf) {
        int row = nf * 16 + cn;
        int kg = (ks * 4 + q) ^ (row & 7);
        bfr[nf] = *(const bf16x8*)((const char*)sB + row * (BK * 2) + kg * 16);
      }
#pragma unroll
      for (int mf = 0; mf < 2; ++mf)
#pragma unroll
        for (int nf = 0; nf < 6; ++nf)
          acc[mf][nf] = __builtin_amdgcn_mfma_f32_16x16x32_bf16(
              af[mf], bfr[nf], acc[mf][nf], 0, 0, 0);
    }
    __syncthreads();
  }

  if (n0 < NLIT) {
    // literal tile: tanh -> LDS -> conj triples (2,4,6) -> formula atomics
#pragma unroll
    for (int nf = 0; nf < 6; ++nf) {
      int col = nf * 16 + cn;
      float bv = bias[n0 + col];
#pragma unroll
      for (int mf = 0; mf < 2; ++mf)
#pragma unroll
        for (int reg = 0; reg < 4; ++reg) {
          int row = wave * 32 + mf * 16 + q * 4 + reg;
          slit[row * LITPAD + col] = fast_tanh(acc[mf][nf][reg] + bv);
        }
    }
    __syncthreads();

    int r = tid >> 1, half = tid & 1;
    const float* lrow = slit + r * LITPAD + half * 48;
    int c0 = ((n0 + half * 48) / 12) * 3;  // first conj of this 48-lit window
    size_t grow = (size_t)(m0 + r) * NFORM;
    float run = 0.f;
    int fprev = -1;
#pragma unroll
    for (int tr = 0; tr < 4; ++tr) {
      const float* p = lrow + tr * 12;
      float s2 = p[0] + p[1];
      float s4 = p[2] + p[3] + p[4] + p[5];
      float s6 = p[6] + p[7] + p[8] + p[9] + p[10] + p[11];
      // conj = tanh(sum - depth + 1.5); triple never crosses a formula
      float v = fast_tanh(s2 - 0.5f) + fast_tanh(s4 - 2.5f) +
                fast_tanh(s6 - 4.5f);
      int c = c0 + tr * 3;
      int f = (c < 384)    ? (c / 6)
              : (c < 960)  ? 64 + (c - 384) / 9
              : (c < 1728) ? 128 + (c - 960) / 12
                           : 192 + (c - 1728) / 15;
      if (f != fprev) {
        if (fprev >= 0) atomicAdd(form_sum + grow + fprev, run);
        fprev = f;
        run = 0.f;
      }
      run += v;
    }
    atomicAdd(form_sum + grow + fprev, run);
  } else {
    // mu tile: store raw x.mu dots
#pragma unroll
    for (int nf = 0; nf < 6; ++nf) {
      int col = n0 - NLIT + nf * 16 + cn;
      if (col < NFORM) {
#pragma unroll
        for (int mf = 0; mf < 2; ++mf)
#pragma unroll
          for (int reg = 0; reg < 4; ++reg) {
            int row = wave * 32 + mf * 16 + q * 4 + reg;
            dotbuf[(size_t)(m0 + row) * NFORM + col] = acc[mf][nf][reg];
          }
      }
    }
  }
}

// ---------------- finale: RBF softmax * dnnf ----------------

__global__ __launch_bounds__(256) void finale(
    const float* __restrict__ form_sum, const float* __restrict__ dotbuf,
    const float* __restrict__ xsq, const float* __restrict__ musq,
    const float* __restrict__ sigma, float* __restrict__ out) {
  int r = blockIdx.x, f = threadIdx.x;
  size_t idx = (size_t)r * NFORM + f;
  float dv = dotbuf[idx];
  float sq = xsq[r] - 2.0f * dv + musq[f];
  float sg = sigma[f];
  float p = __expf(-0.5f * sq / (sg * sg));
  float e = __expf(2.0f * p);  // TEMPERATURE = 2, values in [1, e^2] -> no max-sub needed
  __shared__ float red[256];
  red[f] = e;
  __syncthreads();
  for (int s = 128; s > 0; s >>= 1) {
    if (f < s) red[f] += red[f + s];
    __syncthreads();
  }
  float denom = red[0];
  float dn = fast_tanh(form_sum[idx] + (float)(6 + 3 * (f >> 6)) - 1.5f);
  out[idx] = dn * (e / denom);
}

// ---------------- launch ----------------

extern "C" void kernel_launch(void* const* d_in, const int* in_sizes, int n_in,
                              void* d_out, int out_size, void* d_ws,
                              size_t ws_size, hipStream_t stream) {
  const float* x = (const float*)d_in[0];
  const float* W = (const float*)d_in[1];
  const float* M = (const float*)d_in[2];
  const float* bias = (const float*)d_in[3];
  const float* mu = (const float*)d_in[4];
  const float* sigma = (const float*)d_in[5];
  float* out = (float*)d_out;

  // workspace layout (~37 MB total)
  float* form_sum = (float*)d_ws;                            // 8 MB
  float* dotbuf = form_sum + (size_t)BATCH * NFORM;          // 8 MB
  u16* xb = (u16*)(dotbuf + (size_t)BATCH * NFORM);          // 8 MB
  u16* wt = xb + (size_t)BATCH * IDIM;                       // 11.3 MB
  float* xsq = (float*)(wt + (size_t)WT_ROWS * IDIM);        // 32 KB
  float* musq = xsq + BATCH;                                 // 1 KB

  hipMemsetAsync(form_sum, 0, (size_t)BATCH * NFORM * sizeof(float), stream);
  prep_x<<<BATCH, 256, 0, stream>>>(x, xb, xsq);
  prep_w<<<dim3(NLIT / 32, IDIM / 32), dim3(32, 8), 0, stream>>>(W, M, wt);
  prep_mu<<<288, 256, 0, stream>>>(mu, wt, musq);
  dnnf_gemm<<<dim3(WT_ROWS / BN, BATCH / BM), 256, 0, stream>>>(xb, wt, bias,
                                                                form_sum, dotbuf);
  finale<<<BATCH, 256, 0, stream>>>(form_sum, dotbuf, xsq, musq, sigma, out);
}

// Round 2
// 266.340 us; speedup vs baseline: 1.0874x; 1.0874x over previous
//
#include <hip/hip_runtime.h>

// DNNF fused pipeline for MI355X (gfx950). R2: BM=256 fat-wave GEMM.
// Per-wave 64x96 acc tile (4x6 frags): 10 ds_read_b128 per 24 MFMA, vs 8/12
// in R1 -> LDS read pipe no longer the bottleneck.

#define BATCH 8192
#define IDIM 512
#define NFORM 256
#define NLIT 10752
#define WT_ROWS 11040  // NLIT + 288 (256 mu rows + 32 zero pad -> 3 tiles of 96)

#define BM 256
#define BN 96
#define BK 64
#define LITPAD 97  // floats per lit row in epilogue LDS; %32==1 -> 2-way max

typedef __bf16 bf16x8 __attribute__((ext_vector_type(8)));
typedef float f32x4 __attribute__((ext_vector_type(4)));
typedef unsigned short u16;
typedef unsigned int u32;

__device__ __forceinline__ u16 f2bf(float f) {
  u32 u = __float_as_uint(f);
  u = (u + 0x7fffu + ((u >> 16) & 1u)) >> 16;  // RNE
  return (u16)u;
}

__device__ __forceinline__ float fast_tanh(float x) {
  float e = __expf(2.0f * x);
  return 1.0f - 2.0f * __builtin_amdgcn_rcpf(e + 1.0f);
}

__device__ __forceinline__ void async_cp16(const void* g, void* l) {
  __builtin_amdgcn_global_load_lds(
      (const u32 __attribute__((address_space(1)))*)g,
      (u32 __attribute__((address_space(3)))*)l, 16, 0, 0);
}

// ---------------- prep kernels ----------------

// wave-per-row, barrier-free: lane handles 8 consecutive floats.
__global__ __launch_bounds__(256) void prep_x(const float* __restrict__ x,
                                              u16* __restrict__ xb,
                                              float* __restrict__ xsq) {
  int wave = threadIdx.x >> 6, lane = threadIdx.x & 63;
  int row = blockIdx.x * 4 + wave;
  const float4* px = (const float4*)(x + (size_t)row * IDIM);
  float4 a = px[lane * 2], b = px[lane * 2 + 1];
  uint4 pk;
  pk.x = (u32)f2bf(a.x) | ((u32)f2bf(a.y) << 16);
  pk.y = (u32)f2bf(a.z) | ((u32)f2bf(a.w) << 16);
  pk.z = (u32)f2bf(b.x) | ((u32)f2bf(b.y) << 16);
  pk.w = (u32)f2bf(b.z) | ((u32)f2bf(b.w) << 16);
  ((uint4*)(xb + (size_t)row * IDIM))[lane] = pk;
  float s = a.x * a.x + a.y * a.y + a.z * a.z + a.w * a.w +
            b.x * b.x + b.y * b.y + b.z * b.z + b.w * b.w;
#pragma unroll
  for (int o = 32; o > 0; o >>= 1) s += __shfl_down(s, o);
  if (lane == 0) xsq[row] = s;
}

// Wt[l][k] = W[k][l] * M[k][l], bf16. 32x32 LDS transpose tiles.
__global__ __launch_bounds__(256) void prep_w(const float* __restrict__ W,
                                              const float* __restrict__ M,
                                              u16* __restrict__ wt) {
  __shared__ float tile[32][33];
  int l0 = blockIdx.x * 32, k0 = blockIdx.y * 32;
  int tx = threadIdx.x, ty = threadIdx.y;
#pragma unroll
  for (int i = 0; i < 4; ++i) {
    int kk = ty + i * 8;
    size_t g = (size_t)(k0 + kk) * NLIT + l0 + tx;
    tile[kk][tx] = W[g] * M[g];
  }
  __syncthreads();
#pragma unroll
  for (int i = 0; i < 4; ++i) {
    int ll = ty + i * 8;
    wt[(size_t)(l0 + ll) * IDIM + k0 + tx] = f2bf(tile[tx][ll]);
  }
}

__global__ __launch_bounds__(256) void prep_mu(const float* __restrict__ mu,
                                               u16* __restrict__ wt,
                                               float* __restrict__ musq) {
  int b = blockIdx.x, t = threadIdx.x;
  if (b < 256) {
    float s = 0.f;
#pragma unroll
    for (int j = t; j < IDIM; j += 256) {
      float v = mu[(size_t)b * IDIM + j];
      wt[(size_t)(NLIT + b) * IDIM + j] = f2bf(v);
      s += v * v;
    }
    __shared__ float red[256];
    red[t] = s;
    __syncthreads();
    for (int sh = 128; sh > 0; sh >>= 1) {
      if (t < sh) red[t] += red[t + sh];
      __syncthreads();
    }
    if (t == 0) musq[b] = red[0];
  } else {
    int row = NLIT + 256 + (b - 256);
    for (int j = t; j < IDIM; j += 256) wt[(size_t)row * IDIM + j] = 0;
  }
}

// ---------------- main fused GEMM ----------------
// C/D frag map: col = lane&15, row = (lane>>4)*4 + reg.
// A/B frags K-major in LDS with XOR swizzle kg_phys = kg ^ (row&7):
// global_load_lds chunks stay lane-contiguous, ds_read_b128 conflict-free.

__global__ __launch_bounds__(256, 3) void dnnf_gemm(
    const u16* __restrict__ xb, const u16* __restrict__ wt,
    const float* __restrict__ bias, float* __restrict__ form_sum,
    float* __restrict__ dotbuf) {
  __shared__ __align__(16) char smraw[128 * LITPAD * 4];  // 49664 B
  // staging view: sA = 256x64 bf16 (32 KB), sB = 96x64 bf16 (12 KB)
  float* slit = (float*)smraw;  // epilogue view: 128 x LITPAD floats

  const int tid = threadIdx.x;
  const int wave = tid >> 6, lane = tid & 63;
  const int m0 = blockIdx.y * BM;
  const int n0 = blockIdx.x * BN;
  const int q = lane >> 4, cn = lane & 15;

  // staging addressing (constant over K-loop): chunk c = tid + i*256,
  // r = (tid>>3) + i*32, kg = (tid&7) ^ (r&7) = (tid&7)^((tid>>3)&7).
  const int kg8 = (((tid & 7) ^ ((tid >> 3) & 7))) * 8;
  const u16* pa = xb + (size_t)(m0 + (tid >> 3)) * IDIM + kg8;
  const u16* pb = wt + (size_t)(n0 + (tid >> 3)) * IDIM + kg8;
  char* dstA = smraw + tid * 16;
  char* dstB = smraw + 32768 + tid * 16;

  // fragment LDS offsets for ks=0; ks=1 = offset ^ 64.
  const int kg0_16 = ((q ^ (cn & 7)) << 4);
  int offA[4], offB[6];
#pragma unroll
  for (int mf = 0; mf < 4; ++mf)
    offA[mf] = (wave * 64 + mf * 16 + cn) * (BK * 2) + kg0_16;
#pragma unroll
  for (int nf = 0; nf < 6; ++nf)
    offB[nf] = 32768 + (nf * 16 + cn) * (BK * 2) + kg0_16;

  f32x4 acc[4][6];
#pragma unroll
  for (int a = 0; a < 4; ++a)
#pragma unroll
    for (int b = 0; b < 6; ++b) acc[a][b] = (f32x4){0.f, 0.f, 0.f, 0.f};

  for (int kt = 0; kt < IDIM; kt += BK) {
#pragma unroll
    for (int i = 0; i < 8; ++i)
      async_cp16(pa + (size_t)i * 32 * IDIM, dstA + i * 4096);
#pragma unroll
    for (int i = 0; i < 3; ++i)
      async_cp16(pb + (size_t)i * 32 * IDIM, dstB + i * 4096);
    pa += BK;
    pb += BK;
    __syncthreads();

#pragma unroll
    for (int ks = 0; ks < 2; ++ks) {
      const int x64 = ks ? 64 : 0;
      bf16x8 af[4], bfr[6];
#pragma unroll
      for (int mf = 0; mf < 4; ++mf)
        af[mf] = *(const bf16x8*)(smraw + (offA[mf] ^ x64));
#pragma unroll
      for (int nf = 0; nf < 6; ++nf)
        bfr[nf] = *(const bf16x8*)(smraw + (offB[nf] ^ x64));
#pragma unroll
      for (int mf = 0; mf < 4; ++mf)
#pragma unroll
        for (int nf = 0; nf < 6; ++nf)
          acc[mf][nf] = __builtin_amdgcn_mfma_f32_16x16x32_bf16(
              af[mf], bfr[nf], acc[mf][nf], 0, 0, 0);
    }
    __syncthreads();
  }

  if (n0 < NLIT) {
    float bv[6];
#pragma unroll
    for (int nf = 0; nf < 6; ++nf) bv[nf] = bias[n0 + nf * 16 + cn];

    // two phases of 128 rows each, reusing one 128 x LITPAD LDS tile
#pragma unroll
    for (int ph = 0; ph < 2; ++ph) {
      if (ph) __syncthreads();  // phase-0 reads done before overwrite
      if ((wave >> 1) == ph) {
#pragma unroll
        for (int nf = 0; nf < 6; ++nf) {
          int col = nf * 16 + cn;
#pragma unroll
          for (int mf = 0; mf < 4; ++mf)
#pragma unroll
            for (int reg = 0; reg < 4; ++reg) {
              int lr = (wave & 1) * 64 + mf * 16 + q * 4 + reg;
              slit[lr * LITPAD + col] = fast_tanh(acc[mf][nf][reg] + bv[nf]);
            }
        }
      }
      __syncthreads();

      int r = tid >> 1, half = tid & 1;
      const float* lrow = slit + r * LITPAD + half * 48;
      int c0 = ((n0 + half * 48) / 12) * 3;
      size_t grow = (size_t)(m0 + ph * 128 + r) * NFORM;
      float run = 0.f;
      int fprev = -1;
#pragma unroll
      for (int tr = 0; tr < 4; ++tr) {
        const float* p = lrow + tr * 12;
        float s2 = p[0] + p[1];
        float s4 = p[2] + p[3] + p[4] + p[5];
        float s6 = p[6] + p[7] + p[8] + p[9] + p[10] + p[11];
        float v = fast_tanh(s2 - 0.5f) + fast_tanh(s4 - 2.5f) +
                  fast_tanh(s6 - 4.5f);
        int c = c0 + tr * 3;
        int f = (c < 384)    ? (c / 6)
                : (c < 960)  ? 64 + (c - 384) / 9
                : (c < 1728) ? 128 + (c - 960) / 12
                             : 192 + (c - 1728) / 15;
        if (f != fprev) {
          if (fprev >= 0) atomicAdd(form_sum + grow + fprev, run);
          fprev = f;
          run = 0.f;
        }
        run += v;
      }
      atomicAdd(form_sum + grow + fprev, run);
    }
  } else {
    // mu tile: store raw x.mu dots
#pragma unroll
    for (int nf = 0; nf < 6; ++nf) {
      int col = n0 - NLIT + nf * 16 + cn;
      if (col < NFORM) {
#pragma unroll
        for (int mf = 0; mf < 4; ++mf)
#pragma unroll
          for (int reg = 0; reg < 4; ++reg) {
            int row = wave * 64 + mf * 16 + q * 4 + reg;
            dotbuf[(size_t)(m0 + row) * NFORM + col] = acc[mf][nf][reg];
          }
      }
    }
  }
}

// ---------------- finale: RBF softmax * dnnf (wave-per-row) ----------------

__global__ __launch_bounds__(256) void finale(
    const float* __restrict__ form_sum, const float* __restrict__ dotbuf,
    const float* __restrict__ xsq, const float* __restrict__ musq,
    const float* __restrict__ sigma, float* __restrict__ out) {
  int wave = threadIdx.x >> 6, lane = threadIdx.x & 63;
  int r = blockIdx.x * 4 + wave;
  size_t base = (size_t)r * NFORM;
  float xs = xsq[r];
  float e[4], s = 0.f;
#pragma unroll
  for (int j = 0; j < 4; ++j) {
    int f = j * 64 + lane;
    float sq = xs - 2.0f * dotbuf[base + f] + musq[f];
    float sg = sigma[f];
    float p = __expf(-0.5f * sq / (sg * sg));
    e[j] = __expf(2.0f * p);  // values in [1, e^2]; no max-sub needed
    s += e[j];
  }
#pragma unroll
  for (int o = 32; o > 0; o >>= 1) s += __shfl_xor(s, o);
  float inv = __builtin_amdgcn_rcpf(s);
#pragma unroll
  for (int j = 0; j < 4; ++j) {
    int f = j * 64 + lane;
    float dn = fast_tanh(form_sum[base + f] + (float)(6 + 3 * j) - 1.5f);
    out[base + f] = dn * e[j] * inv;
  }
}

// ---------------- launch ----------------

extern "C" void kernel_launch(void* const* d_in, const int* in_sizes, int n_in,
                              void* d_out, int out_size, void* d_ws,
                              size_t ws_size, hipStream_t stream) {
  const float* x = (const float*)d_in[0];
  const float* W = (const float*)d_in[1];
  const float* M = (const float*)d_in[2];
  const float* bias = (const float*)d_in[3];
  const float* mu = (const float*)d_in[4];
  const float* sigma = (const float*)d_in[5];
  float* out = (float*)d_out;

  float* form_sum = (float*)d_ws;                            // 8 MB
  float* dotbuf = form_sum + (size_t)BATCH * NFORM;          // 8 MB
  u16* xb = (u16*)(dotbuf + (size_t)BATCH * NFORM);          // 8 MB
  u16* wt = xb + (size_t)BATCH * IDIM;                       // 11.3 MB
  float* xsq = (float*)(wt + (size_t)WT_ROWS * IDIM);        // 32 KB
  float* musq = xsq + BATCH;                                 // 1 KB

  hipMemsetAsync(form_sum, 0, (size_t)BATCH * NFORM * sizeof(float), stream);
  prep_x<<<BATCH / 4, 256, 0, stream>>>(x, xb, xsq);
  prep_w<<<dim3(NLIT / 32, IDIM / 32), dim3(32, 8), 0, stream>>>(W, M, wt);
  prep_mu<<<288, 256, 0, stream>>>(mu, wt, musq);
  dnnf_gemm<<<dim3(WT_ROWS / BN, BATCH / BM), 256, 0, stream>>>(xb, wt, bias,
                                                                form_sum, dotbuf);
  finale<<<BATCH / 4, 256, 0, stream>>>(form_sum, dotbuf, xsq, musq, sigma, out);
}

// Round 4
// 245.160 us; speedup vs baseline: 1.1814x; 1.0864x over previous
//
#include <hip/hip_runtime.h>

// DNNF fused pipeline for MI355X (gfx950). R4 = R3 + race fix:
// trailing barrier is now "s_waitcnt lgkmcnt(0); s_barrier" so a wave cannot
// signal buffer-free while its ds_reads are still pending in the DS pipe
// (R3's tripwire failure was this race: next iteration's global_load_lds DMA
// overwrote the buffer under a slow wave's in-flight ds_read).

#define BATCH 8192
#define IDIM 512
#define NFORM 256
#define NLIT 10752
#define WT_ROWS 11136  // NLIT + 256 mu + 128 zero pad; /192 = 58 tiles

#define BM 128
#define BN 192
#define BK 64
#define BUFB 40960  // one LDS buffer: A 16384 B + B 24576 B
#define SLITP 196   // slit row stride (floats); 4*196 % 32 == 16 -> 2-way free

typedef __bf16 bf16x8 __attribute__((ext_vector_type(8)));
typedef float f32x4 __attribute__((ext_vector_type(4)));
typedef unsigned short u16;
typedef unsigned int u32;

__device__ __forceinline__ u16 f2bf(float f) {
  u32 u = __float_as_uint(f);
  u = (u + 0x7fffu + ((u >> 16) & 1u)) >> 16;  // RNE
  return (u16)u;
}

__device__ __forceinline__ float fast_tanh(float x) {
  float e = __expf(2.0f * x);
  return 1.0f - 2.0f * __builtin_amdgcn_rcpf(e + 1.0f);
}

__device__ __forceinline__ void async_cp16(const void* g, void* l) {
  __builtin_amdgcn_global_load_lds(
      (const u32 __attribute__((address_space(1)))*)g,
      (u32 __attribute__((address_space(3)))*)l, 16, 0, 0);
}

// ---------------- fused prep (one dispatch) ----------------

#define PREPX_BLKS 2048
#define PREPW_BLKS 1344  // 168 l-tiles x 8 k-tiles

__global__ __launch_bounds__(256) void prep_all(
    const float* __restrict__ x, const float* __restrict__ W,
    const float* __restrict__ M, const float* __restrict__ mu,
    u16* __restrict__ xb, u16* __restrict__ wt, float* __restrict__ xsq,
    float* __restrict__ musq, float* __restrict__ form_sum) {
  __shared__ float lds[64 * 65];  // 16.6 KB; also reused as red[256]
  const int blk = blockIdx.x, tid = threadIdx.x;

  if (blk < PREPX_BLKS) {
    ((uint4*)form_sum)[blk * 256 + tid] = make_uint4(0, 0, 0, 0);
    int wave = tid >> 6, lane = tid & 63;
    int row = blk * 4 + wave;
    const float4* px = (const float4*)(x + (size_t)row * IDIM);
    float4 a = px[lane * 2], b = px[lane * 2 + 1];
    uint4 pk;
    pk.x = (u32)f2bf(a.x) | ((u32)f2bf(a.y) << 16);
    pk.y = (u32)f2bf(a.z) | ((u32)f2bf(a.w) << 16);
    pk.z = (u32)f2bf(b.x) | ((u32)f2bf(b.y) << 16);
    pk.w = (u32)f2bf(b.z) | ((u32)f2bf(b.w) << 16);
    ((uint4*)(xb + (size_t)row * IDIM))[lane] = pk;
    float s = a.x * a.x + a.y * a.y + a.z * a.z + a.w * a.w +
              b.x * b.x + b.y * b.y + b.z * b.z + b.w * b.w;
#pragma unroll
    for (int o = 32; o > 0; o >>= 1) s += __shfl_down(s, o);
    if (lane == 0) xsq[row] = s;
  } else if (blk < PREPX_BLKS + PREPW_BLKS) {
    int b = blk - PREPX_BLKS;
    int l0 = (b % 168) * 64, k0 = (b / 168) * 64;
#pragma unroll
    for (int j = 0; j < 4; ++j) {
      int idx = tid + j * 256;
      int kk = idx >> 4, l4 = idx & 15;
      size_t g = (size_t)(k0 + kk) * NLIT + l0 + l4 * 4;
      float4 w4 = *(const float4*)(W + g);
      float4 m4 = *(const float4*)(M + g);
      lds[kk * 65 + l4 * 4 + 0] = w4.x * m4.x;
      lds[kk * 65 + l4 * 4 + 1] = w4.y * m4.y;
      lds[kk * 65 + l4 * 4 + 2] = w4.z * m4.z;
      lds[kk * 65 + l4 * 4 + 3] = w4.w * m4.w;
    }
    __syncthreads();
    int l = tid >> 2, kq = tid & 3;
    u32 pk[8];
#pragma unroll
    for (int t = 0; t < 8; ++t) {
      u16 lo = f2bf(lds[(kq * 16 + 2 * t) * 65 + l]);
      u16 hi = f2bf(lds[(kq * 16 + 2 * t + 1) * 65 + l]);
      pk[t] = (u32)lo | ((u32)hi << 16);
    }
    u32* dst = (u32*)(wt + (size_t)(l0 + l) * IDIM + k0 + kq * 16);
    ((uint4*)dst)[0] = make_uint4(pk[0], pk[1], pk[2], pk[3]);
    ((uint4*)dst)[1] = make_uint4(pk[4], pk[5], pk[6], pk[7]);
  } else {
    int b = blk - PREPX_BLKS - PREPW_BLKS;
    if (b < 256) {
      float s = 0.f;
#pragma unroll
      for (int j = tid; j < IDIM; j += 256) {
        float v = mu[(size_t)b * IDIM + j];
        wt[(size_t)(NLIT + b) * IDIM + j] = f2bf(v);
        s += v * v;
      }
      float* red = lds;
      red[tid] = s;
      __syncthreads();
      for (int sh = 128; sh > 0; sh >>= 1) {
        if (tid < sh) red[tid] += red[tid + sh];
        __syncthreads();
      }
      if (tid == 0) musq[b] = red[0];
    } else {
      int row = NLIT + 256 + (b - 256);  // 11008..11135
      for (int j = tid; j < IDIM; j += 256) wt[(size_t)row * IDIM + j] = 0;
    }
  }
}

// ---------------- main fused GEMM (double-buffered) ----------------
// Pipeline per K-tile: issue copies for k+1 into other buffer, then
// s_waitcnt vmcnt(10) (waits only tile-k copies) + s_barrier, compute,
// then s_waitcnt lgkmcnt(0) + s_barrier (ds_reads sampled before the
// buffer is released for the next DMA). Never a vmcnt(0) drain in-loop.

__global__ __launch_bounds__(256, 2) void dnnf_gemm(
    const u16* __restrict__ xb, const u16* __restrict__ wt,
    const float* __restrict__ bias, float* __restrict__ form_sum,
    float* __restrict__ dotbuf) {
  __shared__ __align__(16) char smraw[2 * BUFB];  // 81920 B -> 2 blocks/CU
  float* slit = (float*)smraw;                    // epilogue view 64 x SLITP

  const int tid = threadIdx.x;
  const int wave = tid >> 6, lane = tid & 63;
  const int wm = wave & 1, wn = wave >> 1;
  const int m0 = blockIdx.y * BM, n0 = blockIdx.x * BN;
  const int q = lane >> 4, cn = lane & 15;

  // staging: chunk c = tid + i*256, r = c>>3, kg = (c&7) ^ (r&7)
  const int kg8 = ((tid & 7) ^ ((tid >> 3) & 7)) * 8;
  const u16* pa = xb + (size_t)(m0 + (tid >> 3)) * IDIM + kg8;
  const u16* pb = wt + (size_t)(n0 + (tid >> 3)) * IDIM + kg8;
  const int dA = tid * 16;          // + i*4096, i<4
  const int dB = 16384 + tid * 16;  // + i*4096, i<6

  const int kg0_16 = ((q ^ (cn & 7)) << 4);
  int offA[4], offB[6];
#pragma unroll
  for (int mf = 0; mf < 4; ++mf)
    offA[mf] = (wm * 64 + mf * 16 + cn) * 128 + kg0_16;
#pragma unroll
  for (int nf = 0; nf < 6; ++nf)
    offB[nf] = 16384 + (wn * 96 + nf * 16 + cn) * 128 + kg0_16;

  f32x4 acc[4][6];
#pragma unroll
  for (int a = 0; a < 4; ++a)
#pragma unroll
    for (int b = 0; b < 6; ++b) acc[a][b] = (f32x4){0.f, 0.f, 0.f, 0.f};

  // prologue: tile 0 -> buffer 0
#pragma unroll
  for (int i = 0; i < 4; ++i)
    async_cp16(pa + (size_t)i * 32 * IDIM, smraw + dA + i * 4096);
#pragma unroll
  for (int i = 0; i < 6; ++i)
    async_cp16(pb + (size_t)i * 32 * IDIM, smraw + dB + i * 4096);
  pa += BK;
  pb += BK;

#pragma unroll
  for (int kt = 0; kt < 8; ++kt) {
    const char* bufc = smraw + (kt & 1) * BUFB;
    if (kt < 7) {
      char* bufn = smraw + ((kt + 1) & 1) * BUFB;
#pragma unroll
      for (int i = 0; i < 4; ++i)
        async_cp16(pa + (size_t)i * 32 * IDIM, bufn + dA + i * 4096);
#pragma unroll
      for (int i = 0; i < 6; ++i)
        async_cp16(pb + (size_t)i * 32 * IDIM, bufn + dB + i * 4096);
      pa += BK;
      pb += BK;
      asm volatile("s_waitcnt vmcnt(10)\n\ts_barrier" ::: "memory");
    } else {
      asm volatile("s_waitcnt vmcnt(0)\n\ts_barrier" ::: "memory");
    }
#pragma unroll
    for (int ks = 0; ks < 2; ++ks) {
      const int x64 = ks ? 64 : 0;
      bf16x8 af[4], bfr[6];
#pragma unroll
      for (int mf = 0; mf < 4; ++mf)
        af[mf] = *(const bf16x8*)(bufc + (offA[mf] ^ x64));
#pragma unroll
      for (int nf = 0; nf < 6; ++nf)
        bfr[nf] = *(const bf16x8*)(bufc + (offB[nf] ^ x64));
#pragma unroll
      for (int mf = 0; mf < 4; ++mf)
#pragma unroll
        for (int nf = 0; nf < 6; ++nf)
          acc[mf][nf] = __builtin_amdgcn_mfma_f32_16x16x32_bf16(
              af[mf], bfr[nf], acc[mf][nf], 0, 0, 0);
    }
    // release buffer only after this wave's ds_reads have SAMPLED the LDS
    // (lgkmcnt(0)), not merely been issued — this was R3's race.
    if (kt < 7)
      asm volatile("s_waitcnt lgkmcnt(0)\n\ts_barrier" ::: "memory");
  }
  __syncthreads();  // full drain before LDS reuse as slit

  if (n0 < NLIT) {
    float bv[6];
#pragma unroll
    for (int nf = 0; nf < 6; ++nf) bv[nf] = bias[n0 + wn * 96 + nf * 16 + cn];

    // two phases of 64 rows, one 64 x SLITP slit tile
#pragma unroll
    for (int ph = 0; ph < 2; ++ph) {
      if (ph) __syncthreads();  // phase-0 reads done before overwrite
      if (wm == ph) {
#pragma unroll
        for (int nf = 0; nf < 6; ++nf) {
          int col = wn * 96 + nf * 16 + cn;
#pragma unroll
          for (int mf = 0; mf < 4; ++mf)
#pragma unroll
            for (int reg = 0; reg < 4; ++reg) {
              int lr = mf * 16 + q * 4 + reg;
              slit[lr * SLITP + col] = fast_tanh(acc[mf][nf][reg] + bv[nf]);
            }
        }
      }
      __syncthreads();

      int r = tid >> 2, sub = tid & 3;  // 64 rows x 4 threads (48 lits each)
      const float* lrow = slit + r * SLITP + sub * 48;
      int c0 = ((n0 + sub * 48) / 12) * 3;
      size_t grow = (size_t)(m0 + ph * 64 + r) * NFORM;
      float run = 0.f;
      int fprev = -1;
#pragma unroll
      for (int tr = 0; tr < 4; ++tr) {
        const float* p = lrow + tr * 12;
        float s2 = p[0] + p[1];
        float s4 = p[2] + p[3] + p[4] + p[5];
        float s6 = p[6] + p[7] + p[8] + p[9] + p[10] + p[11];
        float v = fast_tanh(s2 - 0.5f) + fast_tanh(s4 - 2.5f) +
                  fast_tanh(s6 - 4.5f);
        int c = c0 + tr * 3;
        int f = (c < 384)    ? (c / 6)
                : (c < 960)  ? 64 + (c - 384) / 9
                : (c < 1728) ? 128 + (c - 960) / 12
                             : 192 + (c - 1728) / 15;
        if (f != fprev) {
          if (fprev >= 0) atomicAdd(form_sum + grow + fprev, run);
          fprev = f;
          run = 0.f;
        }
        run += v;
      }
      atomicAdd(form_sum + grow + fprev, run);
    }
  } else {
    // mu tiles: store raw x.mu dots
#pragma unroll
    for (int nf = 0; nf < 6; ++nf) {
      int col = n0 - NLIT + wn * 96 + nf * 16 + cn;
      if (col < NFORM) {
#pragma unroll
        for (int mf = 0; mf < 4; ++mf)
#pragma unroll
          for (int reg = 0; reg < 4; ++reg) {
            int row = wm * 64 + mf * 16 + q * 4 + reg;
            dotbuf[(size_t)(m0 + row) * NFORM + col] = acc[mf][nf][reg];
          }
      }
    }
  }
}

// ---------------- finale: RBF softmax * dnnf (wave-per-row) ----------------

__global__ __launch_bounds__(256) void finale(
    const float* __restrict__ form_sum, const float* __restrict__ dotbuf,
    const float* __restrict__ xsq, const float* __restrict__ musq,
    const float* __restrict__ sigma, float* __restrict__ out) {
  int wave = threadIdx.x >> 6, lane = threadIdx.x & 63;
  int r = blockIdx.x * 4 + wave;
  size_t base = (size_t)r * NFORM;
  float xs = xsq[r];
  float e[4], s = 0.f;
#pragma unroll
  for (int j = 0; j < 4; ++j) {
    int f = j * 64 + lane;
    float sq = xs - 2.0f * dotbuf[base + f] + musq[f];
    float sg = sigma[f];
    float p = __expf(-0.5f * sq / (sg * sg));
    e[j] = __expf(2.0f * p);  // TEMPERATURE=2; values in [1, e^2]
    s += e[j];
  }
#pragma unroll
  for (int o = 32; o > 0; o >>= 1) s += __shfl_xor(s, o);
  float inv = __builtin_amdgcn_rcpf(s);
#pragma unroll
  for (int j = 0; j < 4; ++j) {
    int f = j * 64 + lane;
    float dn = fast_tanh(form_sum[base + f] + (float)(6 + 3 * j) - 1.5f);
    out[base + f] = dn * e[j] * inv;
  }
}

// ---------------- launch ----------------

extern "C" void kernel_launch(void* const* d_in, const int* in_sizes, int n_in,
                              void* d_out, int out_size, void* d_ws,
                              size_t ws_size, hipStream_t stream) {
  const float* x = (const float*)d_in[0];
  const float* W = (const float*)d_in[1];
  const float* M = (const float*)d_in[2];
  const float* bias = (const float*)d_in[3];
  const float* mu = (const float*)d_in[4];
  const float* sigma = (const float*)d_in[5];
  float* out = (float*)d_out;

  float* form_sum = (float*)d_ws;                       // 8 MB
  float* dotbuf = form_sum + (size_t)BATCH * NFORM;     // 8 MB
  u16* xb = (u16*)(dotbuf + (size_t)BATCH * NFORM);     // 8 MB
  u16* wt = xb + (size_t)BATCH * IDIM;                  // 11.4 MB
  float* xsq = (float*)(wt + (size_t)WT_ROWS * IDIM);   // 32 KB
  float* musq = xsq + BATCH;                            // 1 KB

  prep_all<<<PREPX_BLKS + PREPW_BLKS + 384, 256, 0, stream>>>(
      x, W, M, mu, xb, wt, xsq, musq, form_sum);
  dnnf_gemm<<<dim3(WT_ROWS / BN, BATCH / BM), 256, 0, stream>>>(xb, wt, bias,
                                                                form_sum, dotbuf);
  finale<<<BATCH / 4, 256, 0, stream>>>(form_sum, dotbuf, xsq, musq, sigma, out);
}

// Round 5
// 234.028 us; speedup vs baseline: 1.2376x; 1.0476x over previous
//
#include <hip/hip_runtime.h>

// DNNF fused pipeline for MI355X (gfx950). R5 = R4 + XCD-locality grid swap:
// grid = (m=64, n=58). id%8 = x%8 since 64%8==0, so each XCD owns 8 FIXED
// m-tiles (1 MB xb pinned in its L2) and streams wt tiles in lockstep with
// the other XCDs (L3 serves 7/8) -> HBM re-fetch collapses.

#define BATCH 8192
#define IDIM 512
#define NFORM 256
#define NLIT 10752
#define WT_ROWS 11136  // NLIT + 256 mu + 128 zero pad; /192 = 58 tiles

#define BM 128
#define BN 192
#define BK 64
#define BUFB 40960  // one LDS buffer: A 16384 B + B 24576 B
#define SLITP 196   // slit row stride (floats)

typedef __bf16 bf16x8 __attribute__((ext_vector_type(8)));
typedef float f32x4 __attribute__((ext_vector_type(4)));
typedef unsigned short u16;
typedef unsigned int u32;

__device__ __forceinline__ u16 f2bf(float f) {
  u32 u = __float_as_uint(f);
  u = (u + 0x7fffu + ((u >> 16) & 1u)) >> 16;  // RNE
  return (u16)u;
}

__device__ __forceinline__ float fast_tanh(float x) {
  float e = __expf(2.0f * x);
  return 1.0f - 2.0f * __builtin_amdgcn_rcpf(e + 1.0f);
}

__device__ __forceinline__ void async_cp16(const void* g, void* l) {
  __builtin_amdgcn_global_load_lds(
      (const u32 __attribute__((address_space(1)))*)g,
      (u32 __attribute__((address_space(3)))*)l, 16, 0, 0);
}

// ---------------- fused prep (one dispatch) ----------------

#define PREPX_BLKS 2048
#define PREPW_BLKS 1344  // 168 l-tiles x 8 k-tiles

__global__ __launch_bounds__(256) void prep_all(
    const float* __restrict__ x, const float* __restrict__ W,
    const float* __restrict__ M, const float* __restrict__ mu,
    u16* __restrict__ xb, u16* __restrict__ wt, float* __restrict__ xsq,
    float* __restrict__ musq, float* __restrict__ form_sum) {
  __shared__ float lds[64 * 65];  // 16.6 KB; also reused as red[256]
  const int blk = blockIdx.x, tid = threadIdx.x;

  if (blk < PREPX_BLKS) {
    ((uint4*)form_sum)[blk * 256 + tid] = make_uint4(0, 0, 0, 0);
    int wave = tid >> 6, lane = tid & 63;
    int row = blk * 4 + wave;
    const float4* px = (const float4*)(x + (size_t)row * IDIM);
    float4 a = px[lane * 2], b = px[lane * 2 + 1];
    uint4 pk;
    pk.x = (u32)f2bf(a.x) | ((u32)f2bf(a.y) << 16);
    pk.y = (u32)f2bf(a.z) | ((u32)f2bf(a.w) << 16);
    pk.z = (u32)f2bf(b.x) | ((u32)f2bf(b.y) << 16);
    pk.w = (u32)f2bf(b.z) | ((u32)f2bf(b.w) << 16);
    ((uint4*)(xb + (size_t)row * IDIM))[lane] = pk;
    float s = a.x * a.x + a.y * a.y + a.z * a.z + a.w * a.w +
              b.x * b.x + b.y * b.y + b.z * b.z + b.w * b.w;
#pragma unroll
    for (int o = 32; o > 0; o >>= 1) s += __shfl_down(s, o);
    if (lane == 0) xsq[row] = s;
  } else if (blk < PREPX_BLKS + PREPW_BLKS) {
    int b = blk - PREPX_BLKS;
    int l0 = (b % 168) * 64, k0 = (b / 168) * 64;
#pragma unroll
    for (int j = 0; j < 4; ++j) {
      int idx = tid + j * 256;
      int kk = idx >> 4, l4 = idx & 15;
      size_t g = (size_t)(k0 + kk) * NLIT + l0 + l4 * 4;
      float4 w4 = *(const float4*)(W + g);
      float4 m4 = *(const float4*)(M + g);
      lds[kk * 65 + l4 * 4 + 0] = w4.x * m4.x;
      lds[kk * 65 + l4 * 4 + 1] = w4.y * m4.y;
      lds[kk * 65 + l4 * 4 + 2] = w4.z * m4.z;
      lds[kk * 65 + l4 * 4 + 3] = w4.w * m4.w;
    }
    __syncthreads();
    int l = tid >> 2, kq = tid & 3;
    u32 pk[8];
#pragma unroll
    for (int t = 0; t < 8; ++t) {
      u16 lo = f2bf(lds[(kq * 16 + 2 * t) * 65 + l]);
      u16 hi = f2bf(lds[(kq * 16 + 2 * t + 1) * 65 + l]);
      pk[t] = (u32)lo | ((u32)hi << 16);
    }
    u32* dst = (u32*)(wt + (size_t)(l0 + l) * IDIM + k0 + kq * 16);
    ((uint4*)dst)[0] = make_uint4(pk[0], pk[1], pk[2], pk[3]);
    ((uint4*)dst)[1] = make_uint4(pk[4], pk[5], pk[6], pk[7]);
  } else {
    int b = blk - PREPX_BLKS - PREPW_BLKS;
    if (b < 256) {
      float s = 0.f;
#pragma unroll
      for (int j = tid; j < IDIM; j += 256) {
        float v = mu[(size_t)b * IDIM + j];
        wt[(size_t)(NLIT + b) * IDIM + j] = f2bf(v);
        s += v * v;
      }
      float* red = lds;
      red[tid] = s;
      __syncthreads();
      for (int sh = 128; sh > 0; sh >>= 1) {
        if (tid < sh) red[tid] += red[tid + sh];
        __syncthreads();
      }
      if (tid == 0) musq[b] = red[0];
    } else {
      int row = NLIT + 256 + (b - 256);  // 11008..11135
      for (int j = tid; j < IDIM; j += 256) wt[(size_t)row * IDIM + j] = 0;
    }
  }
}

// ---------------- main fused GEMM (double-buffered) ----------------
// Pipeline per K-tile: issue copies for k+1 into other buffer, then
// s_waitcnt vmcnt(10) + s_barrier (prefetch stays in flight), compute,
// s_waitcnt lgkmcnt(0) + s_barrier (reads sampled before buffer release).

__global__ __launch_bounds__(256, 2) void dnnf_gemm(
    const u16* __restrict__ xb, const u16* __restrict__ wt,
    const float* __restrict__ bias, float* __restrict__ form_sum,
    float* __restrict__ dotbuf) {
  __shared__ __align__(16) char smraw[2 * BUFB];  // 81920 B -> 2 blocks/CU
  float* slit = (float*)smraw;                    // epilogue view 64 x SLITP

  const int tid = threadIdx.x;
  const int wave = tid >> 6, lane = tid & 63;
  const int wm = wave & 1, wn = wave >> 1;
  // R5 grid swap: x = m (64), y = n (58); XCD = id%8 = x%8 -> per-XCD
  // fixed m-tile set, streaming n.
  const int m0 = blockIdx.x * BM, n0 = blockIdx.y * BN;
  const int q = lane >> 4, cn = lane & 15;

  // staging: chunk c = tid + i*256, r = c>>3, kg = (c&7) ^ (r&7)
  const int kg8 = ((tid & 7) ^ ((tid >> 3) & 7)) * 8;
  const u16* pa = xb + (size_t)(m0 + (tid >> 3)) * IDIM + kg8;
  const u16* pb = wt + (size_t)(n0 + (tid >> 3)) * IDIM + kg8;
  const int dA = tid * 16;          // + i*4096, i<4
  const int dB = 16384 + tid * 16;  // + i*4096, i<6

  const int kg0_16 = ((q ^ (cn & 7)) << 4);
  int offA[4], offB[6];
#pragma unroll
  for (int mf = 0; mf < 4; ++mf)
    offA[mf] = (wm * 64 + mf * 16 + cn) * 128 + kg0_16;
#pragma unroll
  for (int nf = 0; nf < 6; ++nf)
    offB[nf] = 16384 + (wn * 96 + nf * 16 + cn) * 128 + kg0_16;

  f32x4 acc[4][6];
#pragma unroll
  for (int a = 0; a < 4; ++a)
#pragma unroll
    for (int b = 0; b < 6; ++b) acc[a][b] = (f32x4){0.f, 0.f, 0.f, 0.f};

  // prologue: tile 0 -> buffer 0
#pragma unroll
  for (int i = 0; i < 4; ++i)
    async_cp16(pa + (size_t)i * 32 * IDIM, smraw + dA + i * 4096);
#pragma unroll
  for (int i = 0; i < 6; ++i)
    async_cp16(pb + (size_t)i * 32 * IDIM, smraw + dB + i * 4096);
  pa += BK;
  pb += BK;

#pragma unroll
  for (int kt = 0; kt < 8; ++kt) {
    const char* bufc = smraw + (kt & 1) * BUFB;
    if (kt < 7) {
      char* bufn = smraw + ((kt + 1) & 1) * BUFB;
#pragma unroll
      for (int i = 0; i < 4; ++i)
        async_cp16(pa + (size_t)i * 32 * IDIM, bufn + dA + i * 4096);
#pragma unroll
      for (int i = 0; i < 6; ++i)
        async_cp16(pb + (size_t)i * 32 * IDIM, bufn + dB + i * 4096);
      pa += BK;
      pb += BK;
      asm volatile("s_waitcnt vmcnt(10)\n\ts_barrier" ::: "memory");
    } else {
      asm volatile("s_waitcnt vmcnt(0)\n\ts_barrier" ::: "memory");
    }
#pragma unroll
    for (int ks = 0; ks < 2; ++ks) {
      const int x64 = ks ? 64 : 0;
      bf16x8 af[4], bfr[6];
#pragma unroll
      for (int mf = 0; mf < 4; ++mf)
        af[mf] = *(const bf16x8*)(bufc + (offA[mf] ^ x64));
#pragma unroll
      for (int nf = 0; nf < 6; ++nf)
        bfr[nf] = *(const bf16x8*)(bufc + (offB[nf] ^ x64));
#pragma unroll
      for (int mf = 0; mf < 4; ++mf)
#pragma unroll
        for (int nf = 0; nf < 6; ++nf)
          acc[mf][nf] = __builtin_amdgcn_mfma_f32_16x16x32_bf16(
              af[mf], bfr[nf], acc[mf][nf], 0, 0, 0);
    }
    if (kt < 7)
      asm volatile("s_waitcnt lgkmcnt(0)\n\ts_barrier" ::: "memory");
  }
  __syncthreads();  // full drain before LDS reuse as slit

  if (n0 < NLIT) {
    float bv[6];
#pragma unroll
    for (int nf = 0; nf < 6; ++nf) bv[nf] = bias[n0 + wn * 96 + nf * 16 + cn];

    // two phases of 64 rows, one 64 x SLITP slit tile
#pragma unroll
    for (int ph = 0; ph < 2; ++ph) {
      if (ph) __syncthreads();  // phase-0 reads done before overwrite
      if (wm == ph) {
#pragma unroll
        for (int nf = 0; nf < 6; ++nf) {
          int col = wn * 96 + nf * 16 + cn;
#pragma unroll
          for (int mf = 0; mf < 4; ++mf)
#pragma unroll
            for (int reg = 0; reg < 4; ++reg) {
              int lr = mf * 16 + q * 4 + reg;
              slit[lr * SLITP + col] = fast_tanh(acc[mf][nf][reg] + bv[nf]);
            }
        }
      }
      __syncthreads();

      int r = tid >> 2, sub = tid & 3;  // 64 rows x 4 threads (48 lits each)
      const float* lrow = slit + r * SLITP + sub * 48;
      int c0 = ((n0 + sub * 48) / 12) * 3;
      size_t grow = (size_t)(m0 + ph * 64 + r) * NFORM;
      float run = 0.f;
      int fprev = -1;
#pragma unroll
      for (int tr = 0; tr < 4; ++tr) {
        const float* p = lrow + tr * 12;
        float s2 = p[0] + p[1];
        float s4 = p[2] + p[3] + p[4] + p[5];
        float s6 = p[6] + p[7] + p[8] + p[9] + p[10] + p[11];
        float v = fast_tanh(s2 - 0.5f) + fast_tanh(s4 - 2.5f) +
                  fast_tanh(s6 - 4.5f);
        int c = c0 + tr * 3;
        int f = (c < 384)    ? (c / 6)
                : (c < 960)  ? 64 + (c - 384) / 9
                : (c < 1728) ? 128 + (c - 960) / 12
                             : 192 + (c - 1728) / 15;
        if (f != fprev) {
          if (fprev >= 0) atomicAdd(form_sum + grow + fprev, run);
          fprev = f;
          run = 0.f;
        }
        run += v;
      }
      atomicAdd(form_sum + grow + fprev, run);
    }
  } else {
    // mu tiles: store raw x.mu dots
#pragma unroll
    for (int nf = 0; nf < 6; ++nf) {
      int col = n0 - NLIT + wn * 96 + nf * 16 + cn;
      if (col < NFORM) {
#pragma unroll
        for (int mf = 0; mf < 4; ++mf)
#pragma unroll
          for (int reg = 0; reg < 4; ++reg) {
            int row = wm * 64 + mf * 16 + q * 4 + reg;
            dotbuf[(size_t)(m0 + row) * NFORM + col] = acc[mf][nf][reg];
          }
      }
    }
  }
}

// ---------------- finale: RBF softmax * dnnf (wave-per-row) ----------------

__global__ __launch_bounds__(256) void finale(
    const float* __restrict__ form_sum, const float* __restrict__ dotbuf,
    const float* __restrict__ xsq, const float* __restrict__ musq,
    const float* __restrict__ sigma, float* __restrict__ out) {
  int wave = threadIdx.x >> 6, lane = threadIdx.x & 63;
  int r = blockIdx.x * 4 + wave;
  size_t base = (size_t)r * NFORM;
  float xs = xsq[r];
  float e[4], s = 0.f;
#pragma unroll
  for (int j = 0; j < 4; ++j) {
    int f = j * 64 + lane;
    float sq = xs - 2.0f * dotbuf[base + f] + musq[f];
    float sg = sigma[f];
    float p = __expf(-0.5f * sq / (sg * sg));
    e[j] = __expf(2.0f * p);  // TEMPERATURE=2; values in [1, e^2]
    s += e[j];
  }
#pragma unroll
  for (int o = 32; o > 0; o >>= 1) s += __shfl_xor(s, o);
  float inv = __builtin_amdgcn_rcpf(s);
#pragma unroll
  for (int j = 0; j < 4; ++j) {
    int f = j * 64 + lane;
    float dn = fast_tanh(form_sum[base + f] + (float)(6 + 3 * j) - 1.5f);
    out[base + f] = dn * e[j] * inv;
  }
}

// ---------------- launch ----------------

extern "C" void kernel_launch(void* const* d_in, const int* in_sizes, int n_in,
                              void* d_out, int out_size, void* d_ws,
                              size_t ws_size, hipStream_t stream) {
  const float* x = (const float*)d_in[0];
  const float* W = (const float*)d_in[1];
  const float* M = (const float*)d_in[2];
  const float* bias = (const float*)d_in[3];
  const float* mu = (const float*)d_in[4];
  const float* sigma = (const float*)d_in[5];
  float* out = (float*)d_out;

  float* form_sum = (float*)d_ws;                       // 8 MB
  float* dotbuf = form_sum + (size_t)BATCH * NFORM;     // 8 MB
  u16* xb = (u16*)(dotbuf + (size_t)BATCH * NFORM);     // 8 MB
  u16* wt = xb + (size_t)BATCH * IDIM;                  // 11.4 MB
  float* xsq = (float*)(wt + (size_t)WT_ROWS * IDIM);   // 32 KB
  float* musq = xsq + BATCH;                            // 1 KB

  prep_all<<<PREPX_BLKS + PREPW_BLKS + 384, 256, 0, stream>>>(
      x, W, M, mu, xb, wt, xsq, musq, form_sum);
  // grid: x = m (64, multiple of 8 -> XCD-pinned m-tiles), y = n (58)
  dnnf_gemm<<<dim3(BATCH / BM, WT_ROWS / BN), 256, 0, stream>>>(xb, wt, bias,
                                                                form_sum, dotbuf);
  finale<<<BATCH / 4, 256, 0, stream>>>(form_sum, dotbuf, xsq, musq, sigma, out);
}